// Round 1
// baseline (31.802 us; speedup 1.0000x reference)
//
#include <hip/hip_runtime.h>
#include <hip/hip_bf16.h>

// Problem: B=16, N=256, F=64, H=64
// out[b,i,j] = (i==j) ? 1 : sigmoid( sum_h relu(a[b,i,h]+c[b,j,h]+b1[h]) * w2[h] + b2 )
// where a = hs @ w1[:, :64]^T, c = hs @ w1[:, 64:]^T

#define BN 4096   // B*N
#define Fd 64
#define Hd 64
#define Nn 256

// Kernel A: compute a (with b1 folded in) and c. 4 rows per block, 64 h per row.
__global__ __launch_bounds__(256) void prep_kernel(
    const float* __restrict__ hs, const float* __restrict__ w1,
    const float* __restrict__ b1,
    float* __restrict__ aout, float* __restrict__ cout) {
  __shared__ float hs_row[4][Fd];
  const int lr  = threadIdx.x >> 6;        // local row 0..3
  const int h   = threadIdx.x & 63;        // h index 0..63
  const int row = blockIdx.x * 4 + lr;     // global (b*N+n) row

  hs_row[lr][h] = hs[row * Fd + h];
  __syncthreads();

  const float* w1row = w1 + h * (2 * Fd);
  float a = 0.f, c = 0.f;
#pragma unroll
  for (int f = 0; f < Fd; ++f) {
    const float x = hs_row[lr][f];
    a = fmaf(x, w1row[f], a);
    c = fmaf(x, w1row[Fd + f], c);
  }
  aout[row * Hd + h] = a + b1[h];
  cout[row * Hd + h] = c;
}

// Kernel B: 32x32 (i,j) tile per block, 256 threads, 4 outputs per thread.
__global__ __launch_bounds__(256) void pair_kernel(
    const float* __restrict__ a_, const float* __restrict__ c_,
    const float* __restrict__ w2, const float* __restrict__ b2,
    float* __restrict__ out) {
  __shared__ float aT[32][Hd + 1];  // +1 pad: conflict-free
  __shared__ float cT[32][Hd + 1];
  __shared__ float w2s[Hd];

  const int b  = blockIdx.z;
  const int i0 = blockIdx.y * 32;
  const int j0 = blockIdx.x * 32;
  const int t  = threadIdx.x;

  // Stage 32x64 a-tile and c-tile (2048 floats each), 8 per thread.
#pragma unroll
  for (int k = t; k < 32 * Hd; k += 256) {
    const int r = k >> 6, col = k & 63;
    aT[r][col] = a_[((b * Nn) + i0 + r) * Hd + col];
    cT[r][col] = c_[((b * Nn) + j0 + r) * Hd + col];
  }
  if (t < Hd) w2s[t] = w2[t];
  __syncthreads();

  const float bias2 = b2[0];
  const int jj  = t & 31;
  const int ii0 = (t >> 5) * 4;

  float acc[4] = {0.f, 0.f, 0.f, 0.f};
#pragma unroll
  for (int h = 0; h < Hd; ++h) {
    const float cv = cT[jj][h];   // conflict-free (padded)
    const float wv = w2s[h];      // broadcast
#pragma unroll
    for (int u = 0; u < 4; ++u) {
      float z = aT[ii0 + u][h] + cv;   // aT read is a broadcast per 32-lane group
      z = fmaxf(z, 0.f);
      acc[u] = fmaf(z, wv, acc[u]);
    }
  }

#pragma unroll
  for (int u = 0; u < 4; ++u) {
    const int i = i0 + ii0 + u;
    const int j = j0 + jj;
    const float logit = acc[u] + bias2;
    const float s = 1.f / (1.f + __expf(-logit));
    out[(b * Nn + i) * Nn + j] = (i == j) ? 1.0f : s;
  }
}

extern "C" void kernel_launch(void* const* d_in, const int* in_sizes, int n_in,
                              void* d_out, int out_size, void* d_ws, size_t ws_size,
                              hipStream_t stream) {
  const float* hs = (const float*)d_in[0];
  const float* w1 = (const float*)d_in[1];
  const float* b1 = (const float*)d_in[2];
  const float* w2 = (const float*)d_in[3];
  const float* b2 = (const float*)d_in[4];
  float* out = (float*)d_out;

  float* a_ws = (float*)d_ws;                  // BN*Hd floats = 1 MB
  float* c_ws = a_ws + (size_t)BN * Hd;        // 1 MB

  prep_kernel<<<BN / 4, 256, 0, stream>>>(hs, w1, b1, a_ws, c_ws);

  dim3 grid(Nn / 32, Nn / 32, 16);
  pair_kernel<<<grid, 256, 0, stream>>>(a_ws, c_ws, w2, b2, out);
}